// Round 11
// baseline (517.415 us; speedup 1.0000x reference)
//
#include <hip/hip_runtime.h>

#define NN 50000
#define EE 800000
#define DD 128
#define CC 16
#define HCOPIES 64

typedef __attribute__((ext_vector_type(8))) short bf16x8;
typedef __attribute__((ext_vector_type(4))) float f32x4;

__device__ inline unsigned short f2bf(float x) {
    unsigned int u = __float_as_uint(x);
    unsigned int r = (u + 0x7FFFu + ((u >> 16) & 1u)) >> 16;
    return (unsigned short)r;
}
__device__ inline float bf2f(unsigned short h) {
    return __uint_as_float(((unsigned int)h) << 16);
}

// ---------------- privatized degree histogram (packed: src lo16, dst hi16) ----------------
__global__ void k_hist(const int* __restrict__ src, const int* __restrict__ dst,
                       unsigned int* __restrict__ hist) {
    int e = blockIdx.x * blockDim.x + threadIdx.x;
    unsigned int cpy = blockIdx.x & (HCOPIES - 1);
    if (e < EE) {
        int s = src[e];
        int d = dst[e];
        if ((unsigned)s < NN) atomicAdd(&hist[cpy * NN + s], 1u);
        if ((unsigned)d < NN) atomicAdd(&hist[cpy * NN + d], 0x10000u);
    }
}

__global__ void k_reduce_deg(const unsigned int* __restrict__ hist,
                             int* __restrict__ cd,
                             float* __restrict__ iso, float* __restrict__ isi) {
    int i = blockIdx.x * blockDim.x + threadIdx.x;
    if (i < NN) {
        unsigned int sum = 0;
#pragma unroll
        for (int c = 0; c < HCOPIES; ++c) sum += hist[c * NN + i];
        unsigned int csv = sum & 0xFFFFu;
        unsigned int cdv = sum >> 16;
        cd[i] = (int)cdv;
        iso[i] = rsqrtf(fmaxf((float)csv, 1.0f));
        isi[i] = rsqrtf(fmaxf((float)cdv, 1.0f));
    }
}

// ---------------- hierarchical exclusive scan: cd -> rowptr ----------------
#define SBLK 256
#define NBLK_SCAN ((NN + SBLK - 1) / SBLK)   // 196

__global__ __launch_bounds__(SBLK) void k_blocksum(const int* __restrict__ cnt,
                                                   int* __restrict__ partial) {
    __shared__ int s[SBLK];
    int t = threadIdx.x;
    int i = blockIdx.x * SBLK + t;
    int v = (i < NN) ? cnt[i] : 0;
    s[t] = v;
    __syncthreads();
    for (int off = SBLK / 2; off > 0; off >>= 1) {
        if (t < off) s[t] += s[t + off];
        __syncthreads();
    }
    if (t == 0) partial[blockIdx.x] = s[0];
}

__global__ __launch_bounds__(SBLK) void k_scanpartial(const int* __restrict__ partial,
                                                      int* __restrict__ pp,
                                                      int* __restrict__ rowptr) {
    __shared__ int s[SBLK];
    int t = threadIdx.x;
    int v = (t < NBLK_SCAN) ? partial[t] : 0;
    s[t] = v;
    __syncthreads();
    for (int off = 1; off < SBLK; off <<= 1) {
        int x = (t >= off) ? s[t - off] : 0;
        __syncthreads();
        s[t] += x;
        __syncthreads();
    }
    if (t < NBLK_SCAN) pp[t] = s[t] - v;   // exclusive prefix of block partials
    if (t == SBLK - 1) rowptr[NN] = s[t];  // grand total (== EE)
}

__global__ __launch_bounds__(SBLK) void k_writerowptr(const int* __restrict__ cnt,
                                                      const int* __restrict__ pp,
                                                      int* __restrict__ rowptr) {
    __shared__ int s[SBLK];
    int t = threadIdx.x;
    int i = blockIdx.x * SBLK + t;
    int v = (i < NN) ? cnt[i] : 0;
    s[t] = v;
    __syncthreads();
    for (int off = 1; off < SBLK; off <<= 1) {
        int x = (t >= off) ? s[t - off] : 0;
        __syncthreads();
        s[t] += x;
        __syncthreads();
    }
    if (i < NN) rowptr[i] = pp[blockIdx.x] + s[t] - v;
}

// ---------------- CSR fill with folded edge weight (guarded store) ----------------
__global__ void k_fill(const int* __restrict__ src, const int* __restrict__ dst,
                       const float* __restrict__ ew, const float* __restrict__ iso,
                       const float* __restrict__ isi, const int* __restrict__ rowptr,
                       int* __restrict__ cursor, int2* __restrict__ pairs) {
    int e = blockIdx.x * blockDim.x + threadIdx.x;
    if (e < EE) {
        int d = dst[e];
        int s = src[e];
        int pos = atomicAdd(&cursor[d], 1);
        float w = ew[e] * iso[s] * isi[d];
        int2 p;
        p.x = s;
        p.y = __float_as_int(w);
        int idx = rowptr[d] + pos;
        if ((unsigned)idx < EE) pairs[idx] = p;   // defensive: never store wild
    }
}

// ---------------- W prep: fp32 [k][c] -> bf16 hi/lo, transposed layout [c][k] ----------------
__global__ __launch_bounds__(128) void k_prepw(
        const float* __restrict__ W1, const float* __restrict__ W2,
        const float* __restrict__ W3, const float* __restrict__ W4,
        const float* __restrict__ Wr,
        unsigned short* __restrict__ WH, unsigned short* __restrict__ WL) {
    int m = blockIdx.x >> 7;
    int c = blockIdx.x & 127;
    int k = threadIdx.x;
    const float* Wm = (m == 0) ? W1 : (m == 1) ? W2 : (m == 2) ? W3 : (m == 3) ? W4 : Wr;
    float x = Wm[k * 128 + c];
    unsigned short hi = f2bf(x);
    unsigned short lo = f2bf(x - bf2f(hi));
    int off = m * 16384 + c * 128 + k;
    WH[off] = hi;
    WL[off] = lo;
}

// ---------------- plain MFMA GEMM (res path: RES = inputs @ Wr + br) ----------------
#define GTILE 64
__global__ __launch_bounds__(512) void k_gemm_mfma(
        const float* __restrict__ X,
        const unsigned short* __restrict__ Wh, const unsigned short* __restrict__ Wl,
        const float* __restrict__ bias, float* __restrict__ Yf, int M) {
    __shared__ unsigned short Xh[GTILE * 128];
    __shared__ unsigned short Xlo[GTILE * 128];

    const int t = threadIdx.x;
    const int row0 = blockIdx.x * GTILE;
    const float4* X4 = (const float4*)X;

    const int lane = t & 63;
    const int wav = t >> 6;
    const int lr = lane & 15;
    const int lk = lane >> 4;

    bf16x8 bh[4], bl[4];
    {
        const int c = 16 * wav + lr;
#pragma unroll
        for (int k0 = 0; k0 < 4; ++k0) {
            int off = c * 128 + k0 * 32 + lk * 8;
            bh[k0] = *(const bf16x8*)&Wh[off];
            bl[k0] = *(const bf16x8*)&Wl[off];
        }
    }

    for (int i = t; i < GTILE * 32; i += 512) {
        int r = i >> 5;
        int c4 = i & 31;
        int gr = row0 + r;
        float4 v = make_float4(0.f, 0.f, 0.f, 0.f);
        if (gr < M) v = X4[(long long)gr * 32 + c4];
        ushort4 h, lo;
        h.x = f2bf(v.x); lo.x = f2bf(v.x - bf2f(h.x));
        h.y = f2bf(v.y); lo.y = f2bf(v.y - bf2f(h.y));
        h.z = f2bf(v.z); lo.z = f2bf(v.z - bf2f(h.z));
        h.w = f2bf(v.w); lo.w = f2bf(v.w - bf2f(h.w));
        int base = r * 128 + ((c4 * 4) ^ ((r & 7) << 3));
        *(ushort4*)&Xh[base] = h;
        *(ushort4*)&Xlo[base] = lo;
    }
    __syncthreads();

    f32x4 acc[4];
#pragma unroll
    for (int m = 0; m < 4; ++m) acc[m] = (f32x4){0.f, 0.f, 0.f, 0.f};

#pragma unroll
    for (int k0 = 0; k0 < 4; ++k0) {
        const int kbase = k0 * 32 + lk * 8;
        bf16x8 ah[4], al[4];
#pragma unroll
        for (int m = 0; m < 4; ++m) {
            int row = 16 * m + lr;
            int off = row * 128 + (kbase ^ ((row & 7) << 3));
            ah[m] = *(const bf16x8*)&Xh[off];
            al[m] = *(const bf16x8*)&Xlo[off];
        }
#pragma unroll
        for (int m = 0; m < 4; ++m) {
            acc[m] = __builtin_amdgcn_mfma_f32_16x16x32_bf16(ah[m], bh[k0], acc[m], 0, 0, 0);
            acc[m] = __builtin_amdgcn_mfma_f32_16x16x32_bf16(ah[m], bl[k0], acc[m], 0, 0, 0);
            acc[m] = __builtin_amdgcn_mfma_f32_16x16x32_bf16(al[m], bh[k0], acc[m], 0, 0, 0);
        }
    }

    {
        int gc = 16 * wav + lr;
        float bv = bias[gc];
#pragma unroll
        for (int m = 0; m < 4; ++m) {
#pragma unroll
            for (int j = 0; j < 4; ++j) {
                int gr = row0 + 16 * m + lk * 4 + j;
                if (gr < M) Yf[(long long)gr * DD + gc] = acc[m][j] + bv;
            }
        }
    }
}

// ---------------- FUSED GraphConv: CSR-gather -> LDS staging -> MFMA -> epilogue ----------------
// Block = 64 nodes x 128 cols, 512 threads / 8 waves.
// Wave w stages rows 8w..8w+7: per row, lane accumulates cols {2*lane, 2*lane+1}
// over the node's edge list (4-deep MLP, 2 accumulators), converts to hi/lo bf16,
// stores XOR-swizzled to LDS. Then the proven MFMA phase + fused epilogue.
__global__ __launch_bounds__(512) void k_gconv(
        const float* __restrict__ Sf, const unsigned short* __restrict__ Sb,
        const int* __restrict__ rowptr, const int2* __restrict__ pairs,
        const unsigned short* __restrict__ Wh, const unsigned short* __restrict__ Wl,
        const float* __restrict__ bias, const float* __restrict__ RES,
        float* __restrict__ Yf, unsigned short* __restrict__ Yb, int M, int relu) {
    __shared__ unsigned short Xh[GTILE * 128];
    __shared__ unsigned short Xlo[GTILE * 128];

    const int t = threadIdx.x;
    const int row0 = blockIdx.x * GTILE;
    const int lane = t & 63;
    const int wav = t >> 6;
    const int lr = lane & 15;
    const int lk = lane >> 4;

    // W fragments (L2-resident; overlap with staging below)
    bf16x8 bh[4], bl[4];
    {
        const int c = 16 * wav + lr;
#pragma unroll
        for (int k0 = 0; k0 < 4; ++k0) {
            int off = c * 128 + k0 * 32 + lk * 8;
            bh[k0] = *(const bf16x8*)&Wh[off];
            bl[k0] = *(const bf16x8*)&Wl[off];
        }
    }

    // ---- fused gather staging ----
    {
        const int c = lane * 2;            // two logical cols per lane
        const int c4 = lane >> 1;          // float4-slot group
        const int sub = (lane & 1) * 2;    // offset within 4-group
        for (int rr = 0; rr < 8; ++rr) {
            int r = 8 * wav + rr;
            int g = row0 + r;
            float2 a0 = make_float2(0.f, 0.f);
            float2 a1 = make_float2(0.f, 0.f);
            if (g < M) {
                int j = rowptr[g];
                int end = rowptr[g + 1];
                j = max(0, min(j, EE));
                end = max(j, min(end, EE));
                if (Sf) {
                    for (; j + 3 < end; j += 4) {
                        int2 p0 = pairs[j + 0];
                        int2 p1 = pairs[j + 1];
                        int2 p2 = pairs[j + 2];
                        int2 p3 = pairs[j + 3];
                        int c0 = ((unsigned)p0.x < NN) ? p0.x : 0;
                        int c1 = ((unsigned)p1.x < NN) ? p1.x : 0;
                        int c2 = ((unsigned)p2.x < NN) ? p2.x : 0;
                        int c3 = ((unsigned)p3.x < NN) ? p3.x : 0;
                        float2 h0 = *(const float2*)&Sf[c0 * DD + c];
                        float2 h1 = *(const float2*)&Sf[c1 * DD + c];
                        float2 h2 = *(const float2*)&Sf[c2 * DD + c];
                        float2 h3 = *(const float2*)&Sf[c3 * DD + c];
                        float w0 = __int_as_float(p0.y);
                        float w1 = __int_as_float(p1.y);
                        float w2 = __int_as_float(p2.y);
                        float w3 = __int_as_float(p3.y);
                        a0.x = fmaf(h0.x, w0, a0.x); a0.y = fmaf(h0.y, w0, a0.y);
                        a1.x = fmaf(h1.x, w1, a1.x); a1.y = fmaf(h1.y, w1, a1.y);
                        a0.x = fmaf(h2.x, w2, a0.x); a0.y = fmaf(h2.y, w2, a0.y);
                        a1.x = fmaf(h3.x, w3, a1.x); a1.y = fmaf(h3.y, w3, a1.y);
                    }
                    for (; j < end; ++j) {
                        int2 p0 = pairs[j];
                        int c0 = ((unsigned)p0.x < NN) ? p0.x : 0;
                        float w0 = __int_as_float(p0.y);
                        float2 h0 = *(const float2*)&Sf[c0 * DD + c];
                        a0.x = fmaf(h0.x, w0, a0.x); a0.y = fmaf(h0.y, w0, a0.y);
                    }
                } else {
                    for (; j + 3 < end; j += 4) {
                        int2 p0 = pairs[j + 0];
                        int2 p1 = pairs[j + 1];
                        int2 p2 = pairs[j + 2];
                        int2 p3 = pairs[j + 3];
                        int c0 = ((unsigned)p0.x < NN) ? p0.x : 0;
                        int c1 = ((unsigned)p1.x < NN) ? p1.x : 0;
                        int c2 = ((unsigned)p2.x < NN) ? p2.x : 0;
                        int c3 = ((unsigned)p3.x < NN) ? p3.x : 0;
                        ushort2 h0 = *(const ushort2*)&Sb[c0 * DD + c];
                        ushort2 h1 = *(const ushort2*)&Sb[c1 * DD + c];
                        ushort2 h2 = *(const ushort2*)&Sb[c2 * DD + c];
                        ushort2 h3 = *(const ushort2*)&Sb[c3 * DD + c];
                        float w0 = __int_as_float(p0.y);
                        float w1 = __int_as_float(p1.y);
                        float w2 = __int_as_float(p2.y);
                        float w3 = __int_as_float(p3.y);
                        a0.x = fmaf(bf2f(h0.x), w0, a0.x); a0.y = fmaf(bf2f(h0.y), w0, a0.y);
                        a1.x = fmaf(bf2f(h1.x), w1, a1.x); a1.y = fmaf(bf2f(h1.y), w1, a1.y);
                        a0.x = fmaf(bf2f(h2.x), w2, a0.x); a0.y = fmaf(bf2f(h2.y), w2, a0.y);
                        a1.x = fmaf(bf2f(h3.x), w3, a1.x); a1.y = fmaf(bf2f(h3.y), w3, a1.y);
                    }
                    for (; j < end; ++j) {
                        int2 p0 = pairs[j];
                        int c0 = ((unsigned)p0.x < NN) ? p0.x : 0;
                        float w0 = __int_as_float(p0.y);
                        ushort2 h0 = *(const ushort2*)&Sb[c0 * DD + c];
                        a0.x = fmaf(bf2f(h0.x), w0, a0.x); a0.y = fmaf(bf2f(h0.y), w0, a0.y);
                    }
                }
            }
            float ax = a0.x + a1.x;
            float ay = a0.y + a1.y;
            unsigned short hx = f2bf(ax);
            unsigned short hy = f2bf(ay);
            ushort2 hh; hh.x = hx; hh.y = hy;
            ushort2 ll; ll.x = f2bf(ax - bf2f(hx)); ll.y = f2bf(ay - bf2f(hy));
            int base = r * 128 + ((c4 * 4) ^ ((r & 7) << 3)) + sub;
            *(ushort2*)&Xh[base] = hh;
            *(ushort2*)&Xlo[base] = ll;
        }
    }
    __syncthreads();

    // ---- MFMA phase (identical to proven k_gemm_mfma) ----
    f32x4 acc[4];
#pragma unroll
    for (int m = 0; m < 4; ++m) acc[m] = (f32x4){0.f, 0.f, 0.f, 0.f};

#pragma unroll
    for (int k0 = 0; k0 < 4; ++k0) {
        const int kbase = k0 * 32 + lk * 8;
        bf16x8 ah[4], al[4];
#pragma unroll
        for (int m = 0; m < 4; ++m) {
            int row = 16 * m + lr;
            int off = row * 128 + (kbase ^ ((row & 7) << 3));
            ah[m] = *(const bf16x8*)&Xh[off];
            al[m] = *(const bf16x8*)&Xlo[off];
        }
#pragma unroll
        for (int m = 0; m < 4; ++m) {
            acc[m] = __builtin_amdgcn_mfma_f32_16x16x32_bf16(ah[m], bh[k0], acc[m], 0, 0, 0);
            acc[m] = __builtin_amdgcn_mfma_f32_16x16x32_bf16(ah[m], bl[k0], acc[m], 0, 0, 0);
            acc[m] = __builtin_amdgcn_mfma_f32_16x16x32_bf16(al[m], bh[k0], acc[m], 0, 0, 0);
        }
    }

    // ---- epilogue ----
    {
        int gc = 16 * wav + lr;
        float bv = bias[gc];
#pragma unroll
        for (int m = 0; m < 4; ++m) {
#pragma unroll
            for (int j = 0; j < 4; ++j) {
                int gr = row0 + 16 * m + lk * 4 + j;
                if (gr < M) {
                    float a = acc[m][j] + bv;
                    if (RES) a += RES[(long long)gr * DD + gc];
                    if (relu) a = fmaxf(a, 0.f);
                    if (Yb) Yb[(long long)gr * DD + gc] = f2bf(a);
                    else    Yf[(long long)gr * DD + gc] = a;
                }
            }
        }
    }
}

// ---------------- final projection: out[M,16] = X[M,128] @ Wo[128,16] + bo ----------------
__global__ __launch_bounds__(256) void k_gemm_out(
        const float* __restrict__ X, const float* __restrict__ Wo,
        const float* __restrict__ bo, float* __restrict__ Y, int M) {
    __shared__ float Wlds[128 * 16];
    int t = threadIdx.x;
    for (int i = t * 4; i < 128 * 16; i += 256 * 4) {
        *(float4*)&Wlds[i] = *(const float4*)&Wo[i];
    }
    __syncthreads();
    int r = blockIdx.x * blockDim.x + t;
    if (r < M) {
        float acc[16];
#pragma unroll
        for (int j = 0; j < 16; ++j) acc[j] = bo[j];
#pragma unroll
        for (int k = 0; k < 128; k += 4) {
            float4 x = *(const float4*)&X[(long long)r * DD + k];
#pragma unroll
            for (int j = 0; j < 16; ++j) {
                acc[j] += x.x * Wlds[(k + 0) * 16 + j] + x.y * Wlds[(k + 1) * 16 + j]
                        + x.z * Wlds[(k + 2) * 16 + j] + x.w * Wlds[(k + 3) * 16 + j];
            }
        }
#pragma unroll
        for (int j = 0; j < 16; j += 4) {
            float4 o = make_float4(acc[j], acc[j + 1], acc[j + 2], acc[j + 3]);
            *(float4*)&Y[(long long)r * CC + j] = o;
        }
    }
}

extern "C" void kernel_launch(void* const* d_in, const int* in_sizes, int n_in,
                              void* d_out, int out_size, void* d_ws, size_t ws_size,
                              hipStream_t stream) {
    const int*   src = (const int*)d_in[0];
    const int*   dst = (const int*)d_in[1];
    const float* inputs = (const float*)d_in[2];
    const float* ew  = (const float*)d_in[3];
    const float* W1  = (const float*)d_in[4];
    const float* b1  = (const float*)d_in[5];
    const float* W2  = (const float*)d_in[6];
    const float* b2  = (const float*)d_in[7];
    const float* W3  = (const float*)d_in[8];
    const float* b3  = (const float*)d_in[9];
    const float* W4  = (const float*)d_in[10];
    const float* b4  = (const float*)d_in[11];
    const float* Wr  = (const float*)d_in[12];
    const float* br  = (const float*)d_in[13];
    const float* Wo  = (const float*)d_in[14];
    const float* bo  = (const float*)d_in[15];
    float* out = (float*)d_out;

    // workspace layout
    char* p = (char*)d_ws;
    float* iso    = (float*)p; p += sizeof(float) * NN;
    float* isi    = (float*)p; p += sizeof(float) * NN;
    int*   cs     = (int*)p;   p += sizeof(int) * NN;      // reused as WHg after fill
    int*   cd     = (int*)p;   p += sizeof(int) * NN;
    int*   cursor = (int*)p;   p += sizeof(int) * NN;
    int*   rowptr = (int*)p;   p += sizeof(int) * (NN + 1);
    int*   partial= (int*)p;   p += sizeof(int) * NBLK_SCAN;
    int*   pp     = (int*)p;   p += sizeof(int) * NBLK_SCAN;
    p = (char*)(((uintptr_t)p + 255) & ~(uintptr_t)255);
    int2*  pairs  = (int2*)p;  p += sizeof(int2) * EE;
    float* RES    = (float*)p; p += sizeof(float) * (size_t)NN * DD;
    float* G      = (float*)p; p += sizeof(float) * (size_t)NN * DD;
    float* X0     = (float*)p; p += sizeof(float) * (size_t)NN * DD;

    // aliases:
    unsigned short* WHg = (unsigned short*)cs;            // 160KB over cs + part of cd
    unsigned short* WLg = WHg + 5 * 16384;                // 160KB
    unsigned int*   hist = (unsigned int*)G;              // used pre-layers only
    unsigned short* H0  = (unsigned short*)G;             // bf16 dbuf A (12.8MB)
    unsigned short* H1  = H0 + (size_t)NN * DD;           // bf16 dbuf B (12.8MB)

    const int GEMM_GRID = (NN + GTILE - 1) / GTILE;       // 782

    // ---- degrees via privatized histogram ----
    hipMemsetAsync(hist, 0, sizeof(unsigned int) * (size_t)HCOPIES * NN, stream);
    hipMemsetAsync(cursor, 0, sizeof(int) * NN, stream);
    k_hist<<<(EE + 255) / 256, 256, 0, stream>>>(src, dst, hist);
    k_reduce_deg<<<(NN + 255) / 256, 256, 0, stream>>>(hist, cd, iso, isi);
    k_blocksum<<<NBLK_SCAN, SBLK, 0, stream>>>(cd, partial);
    k_scanpartial<<<1, SBLK, 0, stream>>>(partial, pp, rowptr);
    k_writerowptr<<<NBLK_SCAN, SBLK, 0, stream>>>(cd, pp, rowptr);
    k_fill<<<(EE + 255) / 256, 256, 0, stream>>>(src, dst, ew, iso, isi, rowptr, cursor, pairs);

    // ---- prep bf16 hi/lo weights ----
    k_prepw<<<5 * 128, 128, 0, stream>>>(W1, W2, W3, W4, Wr, WHg, WLg);

    // ---- res = inputs @ Wr + br (fp32 out) ----
    k_gemm_mfma<<<GEMM_GRID, 512, 0, stream>>>(inputs, WHg + 4 * 16384, WLg + 4 * 16384,
                                               br, RES, NN);

    // ---- 4 fused GraphConv layers (H double-buffered in G region) ----
    // l=0: inputs(f32) -> H0 ; l=1: H0 -> H1 ; l=2: H1 -> H0 ; l=3: H0 -> X0(f32,+RES)
    k_gconv<<<GEMM_GRID, 512, 0, stream>>>(inputs, nullptr, rowptr, pairs,
                                           WHg + 0 * 16384, WLg + 0 * 16384,
                                           b1, nullptr, nullptr, H0, NN, 1);
    k_gconv<<<GEMM_GRID, 512, 0, stream>>>(nullptr, H0, rowptr, pairs,
                                           WHg + 1 * 16384, WLg + 1 * 16384,
                                           b2, nullptr, nullptr, H1, NN, 1);
    k_gconv<<<GEMM_GRID, 512, 0, stream>>>(nullptr, H1, rowptr, pairs,
                                           WHg + 2 * 16384, WLg + 2 * 16384,
                                           b3, nullptr, nullptr, H0, NN, 1);
    k_gconv<<<GEMM_GRID, 512, 0, stream>>>(nullptr, H0, rowptr, pairs,
                                           WHg + 3 * 16384, WLg + 3 * 16384,
                                           b4, RES, X0, nullptr, NN, 1);

    k_gemm_out<<<(NN + 255) / 256, 256, 0, stream>>>(X0, Wo, bo, out, NN);
}

// Round 12
// 364.519 us; speedup vs baseline: 1.4194x; 1.4194x over previous
//
#include <hip/hip_runtime.h>

#define NN 50000
#define EE 800000
#define DD 128
#define CC 16
#define HCOPIES 64
#define NRANGE 16384   // nodes per LDS-hist range (64KB LDS)

typedef __attribute__((ext_vector_type(8))) short bf16x8;
typedef __attribute__((ext_vector_type(4))) float f32x4;

__device__ inline unsigned short f2bf(float x) {
    unsigned int u = __float_as_uint(x);
    unsigned int r = (u + 0x7FFFu + ((u >> 16) & 1u)) >> 16;
    return (unsigned short)r;
}
__device__ inline float bf2f(unsigned short h) {
    return __uint_as_float(((unsigned int)h) << 16);
}

// ---------------- LDS-privatized degree histogram (packed: src lo16, dst hi16) ----------------
// grid = NRANGES * HCOPIES blocks. Block (r, sub): LDS-hist of node range r over edge
// chunk sub, then non-atomic write of slice r into global copy sub. No global atomics.
__global__ __launch_bounds__(256) void k_hist_lds(
        const int* __restrict__ src, const int* __restrict__ dst,
        unsigned int* __restrict__ hist) {
    __shared__ unsigned int lds[NRANGE];
    const int t = threadIdx.x;
    const int r = blockIdx.x / HCOPIES;
    const int sub = blockIdx.x % HCOPIES;
    const int base = r * NRANGE;
    const int hi = min(base + NRANGE, NN) - base;   // range size (<= NRANGE)

    for (int i = t; i < NRANGE; i += 256) lds[i] = 0;
    __syncthreads();

    const int chunk = EE / HCOPIES;                 // 12500
    const int e0 = sub * chunk;
    const int e1 = e0 + chunk;
    for (int e = e0 + t; e < e1; e += 256) {
        int s = src[e];
        int d = dst[e];
        unsigned us = (unsigned)(s - base);
        unsigned ud = (unsigned)(d - base);
        if (us < (unsigned)hi) atomicAdd(&lds[us], 1u);
        if (ud < (unsigned)hi) atomicAdd(&lds[ud], 0x10000u);
    }
    __syncthreads();

    for (int i = t; i < hi; i += 256) hist[(size_t)sub * NN + base + i] = lds[i];
}

__global__ void k_reduce_deg(const unsigned int* __restrict__ hist,
                             int* __restrict__ cd,
                             float* __restrict__ iso, float* __restrict__ isi) {
    int i = blockIdx.x * blockDim.x + threadIdx.x;
    if (i < NN) {
        unsigned int sum = 0;
#pragma unroll
        for (int c = 0; c < HCOPIES; ++c) sum += hist[(size_t)c * NN + i];
        unsigned int csv = sum & 0xFFFFu;
        unsigned int cdv = sum >> 16;
        cd[i] = (int)cdv;
        iso[i] = rsqrtf(fmaxf((float)csv, 1.0f));
        isi[i] = rsqrtf(fmaxf((float)cdv, 1.0f));
    }
}

// ---------------- hierarchical exclusive scan: cd -> rowptr ----------------
#define SBLK 256
#define NBLK_SCAN ((NN + SBLK - 1) / SBLK)   // 196

__global__ __launch_bounds__(SBLK) void k_blocksum(const int* __restrict__ cnt,
                                                   int* __restrict__ partial) {
    __shared__ int s[SBLK];
    int t = threadIdx.x;
    int i = blockIdx.x * SBLK + t;
    int v = (i < NN) ? cnt[i] : 0;
    s[t] = v;
    __syncthreads();
    for (int off = SBLK / 2; off > 0; off >>= 1) {
        if (t < off) s[t] += s[t + off];
        __syncthreads();
    }
    if (t == 0) partial[blockIdx.x] = s[0];
}

__global__ __launch_bounds__(SBLK) void k_scanpartial(const int* __restrict__ partial,
                                                      int* __restrict__ pp,
                                                      int* __restrict__ rowptr) {
    __shared__ int s[SBLK];
    int t = threadIdx.x;
    int v = (t < NBLK_SCAN) ? partial[t] : 0;
    s[t] = v;
    __syncthreads();
    for (int off = 1; off < SBLK; off <<= 1) {
        int x = (t >= off) ? s[t - off] : 0;
        __syncthreads();
        s[t] += x;
        __syncthreads();
    }
    if (t < NBLK_SCAN) pp[t] = s[t] - v;   // exclusive prefix of block partials
    if (t == SBLK - 1) rowptr[NN] = s[t];  // grand total (== EE)
}

__global__ __launch_bounds__(SBLK) void k_writerowptr(const int* __restrict__ cnt,
                                                      const int* __restrict__ pp,
                                                      int* __restrict__ rowptr) {
    __shared__ int s[SBLK];
    int t = threadIdx.x;
    int i = blockIdx.x * SBLK + t;
    int v = (i < NN) ? cnt[i] : 0;
    s[t] = v;
    __syncthreads();
    for (int off = 1; off < SBLK; off <<= 1) {
        int x = (t >= off) ? s[t - off] : 0;
        __syncthreads();
        s[t] += x;
        __syncthreads();
    }
    if (i < NN) rowptr[i] = pp[blockIdx.x] + s[t] - v;
}

// ---------------- CSR fill with folded edge weight (guarded store) ----------------
__global__ void k_fill(const int* __restrict__ src, const int* __restrict__ dst,
                       const float* __restrict__ ew, const float* __restrict__ iso,
                       const float* __restrict__ isi, const int* __restrict__ rowptr,
                       int* __restrict__ cursor, int2* __restrict__ pairs) {
    int e = blockIdx.x * blockDim.x + threadIdx.x;
    if (e < EE) {
        int d = dst[e];
        int s = src[e];
        int pos = atomicAdd(&cursor[d], 1);
        float w = ew[e] * iso[s] * isi[d];
        int2 p;
        p.x = s;
        p.y = __float_as_int(w);
        int idx = rowptr[d] + pos;
        if ((unsigned)idx < EE) pairs[idx] = p;   // defensive: never store wild
    }
}

// ---------------- CSR gather, fp32 source (layer 0), 4-deep pipelined ----------------
__global__ __launch_bounds__(256) void k_gather(
        const float* __restrict__ X, const int* __restrict__ rowptr,
        const int2* __restrict__ pairs, float* __restrict__ G) {
    int node = blockIdx.x * 4 + (threadIdx.x >> 6);
    if (node >= NN) return;
    int lane = threadIdx.x & 63;
    int c = lane * 2;
    int j = rowptr[node];
    int end = rowptr[node + 1];
    j = max(0, min(j, EE));
    end = max(j, min(end, EE));
    float2 a0 = make_float2(0.f, 0.f);
    float2 a1 = make_float2(0.f, 0.f);
    for (; j + 3 < end; j += 4) {
        int2 p0 = pairs[j + 0];
        int2 p1 = pairs[j + 1];
        int2 p2 = pairs[j + 2];
        int2 p3 = pairs[j + 3];
        int c0 = ((unsigned)p0.x < NN) ? p0.x : 0;
        int c1 = ((unsigned)p1.x < NN) ? p1.x : 0;
        int c2 = ((unsigned)p2.x < NN) ? p2.x : 0;
        int c3 = ((unsigned)p3.x < NN) ? p3.x : 0;
        float2 h0 = *(const float2*)&X[c0 * DD + c];
        float2 h1 = *(const float2*)&X[c1 * DD + c];
        float2 h2 = *(const float2*)&X[c2 * DD + c];
        float2 h3 = *(const float2*)&X[c3 * DD + c];
        float w0 = __int_as_float(p0.y);
        float w1 = __int_as_float(p1.y);
        float w2 = __int_as_float(p2.y);
        float w3 = __int_as_float(p3.y);
        a0.x = fmaf(h0.x, w0, a0.x); a0.y = fmaf(h0.y, w0, a0.y);
        a1.x = fmaf(h1.x, w1, a1.x); a1.y = fmaf(h1.y, w1, a1.y);
        a0.x = fmaf(h2.x, w2, a0.x); a0.y = fmaf(h2.y, w2, a0.y);
        a1.x = fmaf(h3.x, w3, a1.x); a1.y = fmaf(h3.y, w3, a1.y);
    }
    for (; j < end; ++j) {
        int2 p0 = pairs[j];
        int c0 = ((unsigned)p0.x < NN) ? p0.x : 0;
        float w0 = __int_as_float(p0.y);
        float2 h0 = *(const float2*)&X[c0 * DD + c];
        a0.x = fmaf(h0.x, w0, a0.x); a0.y = fmaf(h0.y, w0, a0.y);
    }
    float2 o = make_float2(a0.x + a1.x, a0.y + a1.y);
    *(float2*)&G[node * DD + c] = o;
}

// ---------------- CSR gather, bf16 source (layers 1-3), 4-deep pipelined ----------------
__global__ __launch_bounds__(256) void k_gather_bf(
        const unsigned short* __restrict__ H, const int* __restrict__ rowptr,
        const int2* __restrict__ pairs, float* __restrict__ G) {
    int node = blockIdx.x * 4 + (threadIdx.x >> 6);
    if (node >= NN) return;
    int lane = threadIdx.x & 63;
    int c = lane * 2;
    int j = rowptr[node];
    int end = rowptr[node + 1];
    j = max(0, min(j, EE));
    end = max(j, min(end, EE));
    float2 a0 = make_float2(0.f, 0.f);
    float2 a1 = make_float2(0.f, 0.f);
    for (; j + 3 < end; j += 4) {
        int2 p0 = pairs[j + 0];
        int2 p1 = pairs[j + 1];
        int2 p2 = pairs[j + 2];
        int2 p3 = pairs[j + 3];
        int c0 = ((unsigned)p0.x < NN) ? p0.x : 0;
        int c1 = ((unsigned)p1.x < NN) ? p1.x : 0;
        int c2 = ((unsigned)p2.x < NN) ? p2.x : 0;
        int c3 = ((unsigned)p3.x < NN) ? p3.x : 0;
        ushort2 h0 = *(const ushort2*)&H[c0 * DD + c];
        ushort2 h1 = *(const ushort2*)&H[c1 * DD + c];
        ushort2 h2 = *(const ushort2*)&H[c2 * DD + c];
        ushort2 h3 = *(const ushort2*)&H[c3 * DD + c];
        float w0 = __int_as_float(p0.y);
        float w1 = __int_as_float(p1.y);
        float w2 = __int_as_float(p2.y);
        float w3 = __int_as_float(p3.y);
        a0.x = fmaf(bf2f(h0.x), w0, a0.x); a0.y = fmaf(bf2f(h0.y), w0, a0.y);
        a1.x = fmaf(bf2f(h1.x), w1, a1.x); a1.y = fmaf(bf2f(h1.y), w1, a1.y);
        a0.x = fmaf(bf2f(h2.x), w2, a0.x); a0.y = fmaf(bf2f(h2.y), w2, a0.y);
        a1.x = fmaf(bf2f(h3.x), w3, a1.x); a1.y = fmaf(bf2f(h3.y), w3, a1.y);
    }
    for (; j < end; ++j) {
        int2 p0 = pairs[j];
        int c0 = ((unsigned)p0.x < NN) ? p0.x : 0;
        float w0 = __int_as_float(p0.y);
        ushort2 h0 = *(const ushort2*)&H[c0 * DD + c];
        a0.x = fmaf(bf2f(h0.x), w0, a0.x); a0.y = fmaf(bf2f(h0.y), w0, a0.y);
    }
    float2 o = make_float2(a0.x + a1.x, a0.y + a1.y);
    *(float2*)&G[node * DD + c] = o;
}

// ---------------- W prep: fp32 [k][c] -> bf16 hi/lo, transposed layout [c][k] ----------------
__global__ __launch_bounds__(128) void k_prepw(
        const float* __restrict__ W1, const float* __restrict__ W2,
        const float* __restrict__ W3, const float* __restrict__ W4,
        const float* __restrict__ Wr,
        unsigned short* __restrict__ WH, unsigned short* __restrict__ WL) {
    int m = blockIdx.x >> 7;
    int c = blockIdx.x & 127;
    int k = threadIdx.x;
    const float* Wm = (m == 0) ? W1 : (m == 1) ? W2 : (m == 2) ? W3 : (m == 3) ? W4 : Wr;
    float x = Wm[k * 128 + c];
    unsigned short hi = f2bf(x);
    unsigned short lo = f2bf(x - bf2f(hi));
    int off = m * 16384 + c * 128 + k;
    WH[off] = hi;
    WL[off] = lo;
}

// ---------------- MFMA split-precision GEMM: W in registers, X-only LDS ----------------
// 512 threads / 8 waves; block = 64 rows x 128 cols; wave w owns cols [16w,16w+16).
// acc += Ah*Bh + Ah*Bl + Al*Bh   (residual ~2^-17)
#define GTILE 64
__global__ __launch_bounds__(512) void k_gemm_mfma(
        const float* __restrict__ X,
        const unsigned short* __restrict__ Wh, const unsigned short* __restrict__ Wl,
        const float* __restrict__ bias, const float* __restrict__ RES,
        float* __restrict__ Yf, unsigned short* __restrict__ Yb, int M, int relu) {
    __shared__ unsigned short Xh[GTILE * 128];
    __shared__ unsigned short Xlo[GTILE * 128];

    const int t = threadIdx.x;
    const int row0 = blockIdx.x * GTILE;
    const float4* X4 = (const float4*)X;

    const int lane = t & 63;
    const int wav = t >> 6;
    const int lr = lane & 15;
    const int lk = lane >> 4;

    bf16x8 bh[4], bl[4];
    {
        const int c = 16 * wav + lr;
#pragma unroll
        for (int k0 = 0; k0 < 4; ++k0) {
            int off = c * 128 + k0 * 32 + lk * 8;
            bh[k0] = *(const bf16x8*)&Wh[off];
            bl[k0] = *(const bf16x8*)&Wl[off];
        }
    }

    for (int i = t; i < GTILE * 32; i += 512) {
        int r = i >> 5;
        int c4 = i & 31;
        int gr = row0 + r;
        float4 v = make_float4(0.f, 0.f, 0.f, 0.f);
        if (gr < M) v = X4[(long long)gr * 32 + c4];
        ushort4 h, lo;
        h.x = f2bf(v.x); lo.x = f2bf(v.x - bf2f(h.x));
        h.y = f2bf(v.y); lo.y = f2bf(v.y - bf2f(h.y));
        h.z = f2bf(v.z); lo.z = f2bf(v.z - bf2f(h.z));
        h.w = f2bf(v.w); lo.w = f2bf(v.w - bf2f(h.w));
        int base = r * 128 + ((c4 * 4) ^ ((r & 7) << 3));
        *(ushort4*)&Xh[base] = h;
        *(ushort4*)&Xlo[base] = lo;
    }
    __syncthreads();

    f32x4 acc[4];
#pragma unroll
    for (int m = 0; m < 4; ++m) acc[m] = (f32x4){0.f, 0.f, 0.f, 0.f};

#pragma unroll
    for (int k0 = 0; k0 < 4; ++k0) {
        const int kbase = k0 * 32 + lk * 8;
        bf16x8 ah[4], al[4];
#pragma unroll
        for (int m = 0; m < 4; ++m) {
            int row = 16 * m + lr;
            int off = row * 128 + (kbase ^ ((row & 7) << 3));
            ah[m] = *(const bf16x8*)&Xh[off];
            al[m] = *(const bf16x8*)&Xlo[off];
        }
#pragma unroll
        for (int m = 0; m < 4; ++m) {
            acc[m] = __builtin_amdgcn_mfma_f32_16x16x32_bf16(ah[m], bh[k0], acc[m], 0, 0, 0);
            acc[m] = __builtin_amdgcn_mfma_f32_16x16x32_bf16(ah[m], bl[k0], acc[m], 0, 0, 0);
            acc[m] = __builtin_amdgcn_mfma_f32_16x16x32_bf16(al[m], bh[k0], acc[m], 0, 0, 0);
        }
    }

    {
        int gc = 16 * wav + lr;
        float bv = bias[gc];
#pragma unroll
        for (int m = 0; m < 4; ++m) {
#pragma unroll
            for (int j = 0; j < 4; ++j) {
                int gr = row0 + 16 * m + lk * 4 + j;
                if (gr < M) {
                    float a = acc[m][j] + bv;
                    if (RES) a += RES[(long long)gr * DD + gc];
                    if (relu) a = fmaxf(a, 0.f);
                    if (Yb) Yb[(long long)gr * DD + gc] = f2bf(a);
                    else    Yf[(long long)gr * DD + gc] = a;
                }
            }
        }
    }
}

// ---------------- final projection: out[M,16] = X[M,128] @ Wo[128,16] + bo ----------------
__global__ __launch_bounds__(256) void k_gemm_out(
        const float* __restrict__ X, const float* __restrict__ Wo,
        const float* __restrict__ bo, float* __restrict__ Y, int M) {
    __shared__ float Wlds[128 * 16];
    int t = threadIdx.x;
    for (int i = t * 4; i < 128 * 16; i += 256 * 4) {
        *(float4*)&Wlds[i] = *(const float4*)&Wo[i];
    }
    __syncthreads();
    int r = blockIdx.x * blockDim.x + t;
    if (r < M) {
        float acc[16];
#pragma unroll
        for (int j = 0; j < 16; ++j) acc[j] = bo[j];
#pragma unroll
        for (int k = 0; k < 128; k += 4) {
            float4 x = *(const float4*)&X[(long long)r * DD + k];
#pragma unroll
            for (int j = 0; j < 16; ++j) {
                acc[j] += x.x * Wlds[(k + 0) * 16 + j] + x.y * Wlds[(k + 1) * 16 + j]
                        + x.z * Wlds[(k + 2) * 16 + j] + x.w * Wlds[(k + 3) * 16 + j];
            }
        }
#pragma unroll
        for (int j = 0; j < 16; j += 4) {
            float4 o = make_float4(acc[j], acc[j + 1], acc[j + 2], acc[j + 3]);
            *(float4*)&Y[(long long)r * CC + j] = o;
        }
    }
}

extern "C" void kernel_launch(void* const* d_in, const int* in_sizes, int n_in,
                              void* d_out, int out_size, void* d_ws, size_t ws_size,
                              hipStream_t stream) {
    const int*   src = (const int*)d_in[0];
    const int*   dst = (const int*)d_in[1];
    const float* inputs = (const float*)d_in[2];
    const float* ew  = (const float*)d_in[3];
    const float* W1  = (const float*)d_in[4];
    const float* b1  = (const float*)d_in[5];
    const float* W2  = (const float*)d_in[6];
    const float* b2  = (const float*)d_in[7];
    const float* W3  = (const float*)d_in[8];
    const float* b3  = (const float*)d_in[9];
    const float* W4  = (const float*)d_in[10];
    const float* b4  = (const float*)d_in[11];
    const float* Wr  = (const float*)d_in[12];
    const float* br  = (const float*)d_in[13];
    const float* Wo  = (const float*)d_in[14];
    const float* bo  = (const float*)d_in[15];
    float* out = (float*)d_out;

    // workspace layout
    char* p = (char*)d_ws;
    float* iso    = (float*)p; p += sizeof(float) * NN;
    float* isi    = (float*)p; p += sizeof(float) * NN;
    int*   cs     = (int*)p;   p += sizeof(int) * NN;      // reused as WHg
    int*   cd     = (int*)p;   p += sizeof(int) * NN;
    int*   cursor = (int*)p;   p += sizeof(int) * NN;
    int*   rowptr = (int*)p;   p += sizeof(int) * (NN + 1);
    int*   partial= (int*)p;   p += sizeof(int) * NBLK_SCAN;
    int*   pp     = (int*)p;   p += sizeof(int) * NBLK_SCAN;
    p = (char*)(((uintptr_t)p + 255) & ~(uintptr_t)255);
    int2*  pairs  = (int2*)p;  p += sizeof(int2) * EE;
    float* RES    = (float*)p; p += sizeof(float) * (size_t)NN * DD;
    float* G      = (float*)p; p += sizeof(float) * (size_t)NN * DD;
    float* X0     = (float*)p; p += sizeof(float) * (size_t)NN * DD;

    // aliases:
    unsigned short* WHg = (unsigned short*)cs;            // 160KB (cs + part of cd)
    unsigned short* WLg = WHg + 5 * 16384;                // 160KB
    unsigned int*   hist = (unsigned int*)G;              // 64 copies x 50K = 12.8MB, pre-layers
    unsigned short* H   = (unsigned short*)X0;            // bf16 intermediate (12.8MB)

    const int GEMM_GRID = (NN + GTILE - 1) / GTILE;       // 782
    const int NRANGES = (NN + NRANGE - 1) / NRANGE;       // 4

    // ---- degrees via LDS-privatized histogram (no global atomics, no memset) ----
    hipMemsetAsync(cursor, 0, sizeof(int) * NN, stream);
    k_hist_lds<<<NRANGES * HCOPIES, 256, 0, stream>>>(src, dst, hist);
    k_reduce_deg<<<(NN + 255) / 256, 256, 0, stream>>>(hist, cd, iso, isi);
    k_blocksum<<<NBLK_SCAN, SBLK, 0, stream>>>(cd, partial);
    k_scanpartial<<<1, SBLK, 0, stream>>>(partial, pp, rowptr);
    k_writerowptr<<<NBLK_SCAN, SBLK, 0, stream>>>(cd, pp, rowptr);
    k_fill<<<(EE + 255) / 256, 256, 0, stream>>>(src, dst, ew, iso, isi, rowptr, cursor, pairs);

    // ---- prep bf16 hi/lo weights ----
    k_prepw<<<5 * 128, 128, 0, stream>>>(W1, W2, W3, W4, Wr, WHg, WLg);

    // ---- res = inputs @ Wr + br (fp32 out) ----
    k_gemm_mfma<<<GEMM_GRID, 512, 0, stream>>>(inputs, WHg + 4 * 16384, WLg + 4 * 16384,
                                               br, nullptr, RES, nullptr, NN, 0);

    const float* bs[4] = {b1, b2, b3, b4};
    for (int l = 0; l < 4; ++l) {
        if (l == 0)
            k_gather<<<(NN + 3) / 4, 256, 0, stream>>>(inputs, rowptr, pairs, G);
        else
            k_gather_bf<<<(NN + 3) / 4, 256, 0, stream>>>(H, rowptr, pairs, G);

        if (l < 3) {
            k_gemm_mfma<<<GEMM_GRID, 512, 0, stream>>>(G, WHg + l * 16384, WLg + l * 16384,
                                                       bs[l], nullptr, nullptr, H, NN, 1);
        } else {
            k_gemm_mfma<<<GEMM_GRID, 512, 0, stream>>>(G, WHg + l * 16384, WLg + l * 16384,
                                                       bs[l], RES, X0, nullptr, NN, 1);
        }
    }

    k_gemm_out<<<(NN + 255) / 256, 256, 0, stream>>>(X0, Wo, bo, out, NN);
}

// Round 13
// 360.522 us; speedup vs baseline: 1.4352x; 1.0111x over previous
//
#include <hip/hip_runtime.h>

#define NN 50000
#define EE 800000
#define DD 128
#define CC 16
#define HCOPIES 64
#define NRANGE 16384   // nodes per LDS-hist range (64KB LDS)

typedef __attribute__((ext_vector_type(8))) short bf16x8;
typedef __attribute__((ext_vector_type(4))) float f32x4;

__device__ inline unsigned short f2bf(float x) {
    unsigned int u = __float_as_uint(x);
    unsigned int r = (u + 0x7FFFu + ((u >> 16) & 1u)) >> 16;
    return (unsigned short)r;
}
__device__ inline float bf2f(unsigned short h) {
    return __uint_as_float(((unsigned int)h) << 16);
}

// ---------------- LDS-privatized degree histogram (packed: src lo16, dst hi16) ----------------
__global__ __launch_bounds__(256) void k_hist_lds(
        const int* __restrict__ src, const int* __restrict__ dst,
        unsigned int* __restrict__ hist) {
    __shared__ unsigned int lds[NRANGE];
    const int t = threadIdx.x;
    const int r = blockIdx.x / HCOPIES;
    const int sub = blockIdx.x % HCOPIES;
    const int base = r * NRANGE;
    const int hi = min(base + NRANGE, NN) - base;   // range size (<= NRANGE)

    for (int i = t; i < NRANGE; i += 256) lds[i] = 0;
    __syncthreads();

    const int chunk = EE / HCOPIES;                 // 12500
    const int e0 = sub * chunk;
    const int e1 = e0 + chunk;
    for (int e = e0 + t; e < e1; e += 256) {
        int s = src[e];
        int d = dst[e];
        unsigned us = (unsigned)(s - base);
        unsigned ud = (unsigned)(d - base);
        if (us < (unsigned)hi) atomicAdd(&lds[us], 1u);
        if (ud < (unsigned)hi) atomicAdd(&lds[ud], 0x10000u);
    }
    __syncthreads();

    for (int i = t; i < hi; i += 256) hist[(size_t)sub * NN + base + i] = lds[i];
}

__global__ void k_reduce_deg(const unsigned int* __restrict__ hist,
                             int* __restrict__ cd,
                             float* __restrict__ iso, float* __restrict__ isi) {
    int i = blockIdx.x * blockDim.x + threadIdx.x;
    if (i < NN) {
        unsigned int sum = 0;
#pragma unroll
        for (int c = 0; c < HCOPIES; ++c) sum += hist[(size_t)c * NN + i];
        unsigned int csv = sum & 0xFFFFu;
        unsigned int cdv = sum >> 16;
        cd[i] = (int)cdv;
        iso[i] = rsqrtf(fmaxf((float)csv, 1.0f));
        isi[i] = rsqrtf(fmaxf((float)cdv, 1.0f));
    }
}

// ---------------- hierarchical exclusive scan: cd -> rowptr ----------------
#define SBLK 256
#define NBLK_SCAN ((NN + SBLK - 1) / SBLK)   // 196

__global__ __launch_bounds__(SBLK) void k_blocksum(const int* __restrict__ cnt,
                                                   int* __restrict__ partial) {
    __shared__ int s[SBLK];
    int t = threadIdx.x;
    int i = blockIdx.x * SBLK + t;
    int v = (i < NN) ? cnt[i] : 0;
    s[t] = v;
    __syncthreads();
    for (int off = SBLK / 2; off > 0; off >>= 1) {
        if (t < off) s[t] += s[t + off];
        __syncthreads();
    }
    if (t == 0) partial[blockIdx.x] = s[0];
}

__global__ __launch_bounds__(SBLK) void k_scanpartial(const int* __restrict__ partial,
                                                      int* __restrict__ pp,
                                                      int* __restrict__ rowptr) {
    __shared__ int s[SBLK];
    int t = threadIdx.x;
    int v = (t < NBLK_SCAN) ? partial[t] : 0;
    s[t] = v;
    __syncthreads();
    for (int off = 1; off < SBLK; off <<= 1) {
        int x = (t >= off) ? s[t - off] : 0;
        __syncthreads();
        s[t] += x;
        __syncthreads();
    }
    if (t < NBLK_SCAN) pp[t] = s[t] - v;   // exclusive prefix of block partials
    if (t == SBLK - 1) rowptr[NN] = s[t];  // grand total (== EE)
}

__global__ __launch_bounds__(SBLK) void k_writerowptr(const int* __restrict__ cnt,
                                                      const int* __restrict__ pp,
                                                      int* __restrict__ rowptr) {
    __shared__ int s[SBLK];
    int t = threadIdx.x;
    int i = blockIdx.x * SBLK + t;
    int v = (i < NN) ? cnt[i] : 0;
    s[t] = v;
    __syncthreads();
    for (int off = 1; off < SBLK; off <<= 1) {
        int x = (t >= off) ? s[t - off] : 0;
        __syncthreads();
        s[t] += x;
        __syncthreads();
    }
    if (i < NN) rowptr[i] = pp[blockIdx.x] + s[t] - v;
}

// ---------------- CSR fill with folded edge weight (guarded store) ----------------
__global__ void k_fill(const int* __restrict__ src, const int* __restrict__ dst,
                       const float* __restrict__ ew, const float* __restrict__ iso,
                       const float* __restrict__ isi, const int* __restrict__ rowptr,
                       int* __restrict__ cursor, int2* __restrict__ pairs) {
    int e = blockIdx.x * blockDim.x + threadIdx.x;
    if (e < EE) {
        int d = dst[e];
        int s = src[e];
        int pos = atomicAdd(&cursor[d], 1);
        float w = ew[e] * iso[s] * isi[d];
        int2 p;
        p.x = s;
        p.y = __float_as_int(w);
        int idx = rowptr[d] + pos;
        if ((unsigned)idx < EE) pairs[idx] = p;   // defensive: never store wild
    }
}

// ---------------- inputs fp32 -> bf16 (for layer-0 gather) ----------------
__global__ __launch_bounds__(256) void k_tobf(const float* __restrict__ X,
                                              unsigned short* __restrict__ Hb) {
    int i = blockIdx.x * blockDim.x + threadIdx.x;   // NN*DD/4 threads
    if (i < NN * DD / 4) {
        float4 v = *(const float4*)&X[i * 4];
        ushort4 h;
        h.x = f2bf(v.x); h.y = f2bf(v.y); h.z = f2bf(v.z); h.w = f2bf(v.w);
        *(ushort4*)&Hb[i * 4] = h;
    }
}

// ---------------- CSR gather, bf16 source, 8-deep pipelined ----------------
__global__ __launch_bounds__(256) void k_gather_bf(
        const unsigned short* __restrict__ H, const int* __restrict__ rowptr,
        const int2* __restrict__ pairs, float* __restrict__ G) {
    int node = blockIdx.x * 4 + (threadIdx.x >> 6);
    if (node >= NN) return;
    int lane = threadIdx.x & 63;
    int c = lane * 2;
    int j = rowptr[node];
    int end = rowptr[node + 1];
    j = max(0, min(j, EE));
    end = max(j, min(end, EE));
    float2 a0 = make_float2(0.f, 0.f);
    float2 a1 = make_float2(0.f, 0.f);
    float2 a2 = make_float2(0.f, 0.f);
    float2 a3 = make_float2(0.f, 0.f);
    for (; j + 7 < end; j += 8) {
        int2 p0 = pairs[j + 0];
        int2 p1 = pairs[j + 1];
        int2 p2 = pairs[j + 2];
        int2 p3 = pairs[j + 3];
        int2 p4 = pairs[j + 4];
        int2 p5 = pairs[j + 5];
        int2 p6 = pairs[j + 6];
        int2 p7 = pairs[j + 7];
        int c0 = ((unsigned)p0.x < NN) ? p0.x : 0;
        int c1 = ((unsigned)p1.x < NN) ? p1.x : 0;
        int c2 = ((unsigned)p2.x < NN) ? p2.x : 0;
        int c3 = ((unsigned)p3.x < NN) ? p3.x : 0;
        int c4 = ((unsigned)p4.x < NN) ? p4.x : 0;
        int c5 = ((unsigned)p5.x < NN) ? p5.x : 0;
        int c6 = ((unsigned)p6.x < NN) ? p6.x : 0;
        int c7 = ((unsigned)p7.x < NN) ? p7.x : 0;
        ushort2 h0 = *(const ushort2*)&H[c0 * DD + c];
        ushort2 h1 = *(const ushort2*)&H[c1 * DD + c];
        ushort2 h2 = *(const ushort2*)&H[c2 * DD + c];
        ushort2 h3 = *(const ushort2*)&H[c3 * DD + c];
        ushort2 h4 = *(const ushort2*)&H[c4 * DD + c];
        ushort2 h5 = *(const ushort2*)&H[c5 * DD + c];
        ushort2 h6 = *(const ushort2*)&H[c6 * DD + c];
        ushort2 h7 = *(const ushort2*)&H[c7 * DD + c];
        float w0 = __int_as_float(p0.y);
        float w1 = __int_as_float(p1.y);
        float w2 = __int_as_float(p2.y);
        float w3 = __int_as_float(p3.y);
        float w4 = __int_as_float(p4.y);
        float w5 = __int_as_float(p5.y);
        float w6 = __int_as_float(p6.y);
        float w7 = __int_as_float(p7.y);
        a0.x = fmaf(bf2f(h0.x), w0, a0.x); a0.y = fmaf(bf2f(h0.y), w0, a0.y);
        a1.x = fmaf(bf2f(h1.x), w1, a1.x); a1.y = fmaf(bf2f(h1.y), w1, a1.y);
        a2.x = fmaf(bf2f(h2.x), w2, a2.x); a2.y = fmaf(bf2f(h2.y), w2, a2.y);
        a3.x = fmaf(bf2f(h3.x), w3, a3.x); a3.y = fmaf(bf2f(h3.y), w3, a3.y);
        a0.x = fmaf(bf2f(h4.x), w4, a0.x); a0.y = fmaf(bf2f(h4.y), w4, a0.y);
        a1.x = fmaf(bf2f(h5.x), w5, a1.x); a1.y = fmaf(bf2f(h5.y), w5, a1.y);
        a2.x = fmaf(bf2f(h6.x), w6, a2.x); a2.y = fmaf(bf2f(h6.y), w6, a2.y);
        a3.x = fmaf(bf2f(h7.x), w7, a3.x); a3.y = fmaf(bf2f(h7.y), w7, a3.y);
    }
    for (; j < end; ++j) {
        int2 p0 = pairs[j];
        int c0 = ((unsigned)p0.x < NN) ? p0.x : 0;
        float w0 = __int_as_float(p0.y);
        ushort2 h0 = *(const ushort2*)&H[c0 * DD + c];
        a0.x = fmaf(bf2f(h0.x), w0, a0.x); a0.y = fmaf(bf2f(h0.y), w0, a0.y);
    }
    float2 o = make_float2((a0.x + a1.x) + (a2.x + a3.x),
                           (a0.y + a1.y) + (a2.y + a3.y));
    *(float2*)&G[node * DD + c] = o;
}

// ---------------- W prep: fp32 [k][c] -> bf16 hi/lo, transposed layout [c][k] ----------------
__global__ __launch_bounds__(128) void k_prepw(
        const float* __restrict__ W1, const float* __restrict__ W2,
        const float* __restrict__ W3, const float* __restrict__ W4,
        const float* __restrict__ Wr,
        unsigned short* __restrict__ WH, unsigned short* __restrict__ WL) {
    int m = blockIdx.x >> 7;
    int c = blockIdx.x & 127;
    int k = threadIdx.x;
    const float* Wm = (m == 0) ? W1 : (m == 1) ? W2 : (m == 2) ? W3 : (m == 3) ? W4 : Wr;
    float x = Wm[k * 128 + c];
    unsigned short hi = f2bf(x);
    unsigned short lo = f2bf(x - bf2f(hi));
    int off = m * 16384 + c * 128 + k;
    WH[off] = hi;
    WL[off] = lo;
}

// ---------------- MFMA split-precision GEMM: W in registers, X-only LDS ----------------
// 512 threads / 8 waves; block = 64 rows x 128 cols; wave w owns cols [16w,16w+16).
// acc += Ah*Bh + Ah*Bl + Al*Bh   (residual ~2^-17)
#define GTILE 64
__global__ __launch_bounds__(512) void k_gemm_mfma(
        const float* __restrict__ X,
        const unsigned short* __restrict__ Wh, const unsigned short* __restrict__ Wl,
        const float* __restrict__ bias, const float* __restrict__ RES,
        float* __restrict__ Yf, unsigned short* __restrict__ Yb, int M, int relu) {
    __shared__ unsigned short Xh[GTILE * 128];
    __shared__ unsigned short Xlo[GTILE * 128];

    const int t = threadIdx.x;
    const int row0 = blockIdx.x * GTILE;
    const float4* X4 = (const float4*)X;

    const int lane = t & 63;
    const int wav = t >> 6;
    const int lr = lane & 15;
    const int lk = lane >> 4;

    bf16x8 bh[4], bl[4];
    {
        const int c = 16 * wav + lr;
#pragma unroll
        for (int k0 = 0; k0 < 4; ++k0) {
            int off = c * 128 + k0 * 32 + lk * 8;
            bh[k0] = *(const bf16x8*)&Wh[off];
            bl[k0] = *(const bf16x8*)&Wl[off];
        }
    }

    for (int i = t; i < GTILE * 32; i += 512) {
        int r = i >> 5;
        int c4 = i & 31;
        int gr = row0 + r;
        float4 v = make_float4(0.f, 0.f, 0.f, 0.f);
        if (gr < M) v = X4[(long long)gr * 32 + c4];
        ushort4 h, lo;
        h.x = f2bf(v.x); lo.x = f2bf(v.x - bf2f(h.x));
        h.y = f2bf(v.y); lo.y = f2bf(v.y - bf2f(h.y));
        h.z = f2bf(v.z); lo.z = f2bf(v.z - bf2f(h.z));
        h.w = f2bf(v.w); lo.w = f2bf(v.w - bf2f(h.w));
        int base = r * 128 + ((c4 * 4) ^ ((r & 7) << 3));
        *(ushort4*)&Xh[base] = h;
        *(ushort4*)&Xlo[base] = lo;
    }
    __syncthreads();

    f32x4 acc[4];
#pragma unroll
    for (int m = 0; m < 4; ++m) acc[m] = (f32x4){0.f, 0.f, 0.f, 0.f};

#pragma unroll
    for (int k0 = 0; k0 < 4; ++k0) {
        const int kbase = k0 * 32 + lk * 8;
        bf16x8 ah[4], al[4];
#pragma unroll
        for (int m = 0; m < 4; ++m) {
            int row = 16 * m + lr;
            int off = row * 128 + (kbase ^ ((row & 7) << 3));
            ah[m] = *(const bf16x8*)&Xh[off];
            al[m] = *(const bf16x8*)&Xlo[off];
        }
#pragma unroll
        for (int m = 0; m < 4; ++m) {
            acc[m] = __builtin_amdgcn_mfma_f32_16x16x32_bf16(ah[m], bh[k0], acc[m], 0, 0, 0);
            acc[m] = __builtin_amdgcn_mfma_f32_16x16x32_bf16(ah[m], bl[k0], acc[m], 0, 0, 0);
            acc[m] = __builtin_amdgcn_mfma_f32_16x16x32_bf16(al[m], bh[k0], acc[m], 0, 0, 0);
        }
    }

    {
        int gc = 16 * wav + lr;
        float bv = bias[gc];
#pragma unroll
        for (int m = 0; m < 4; ++m) {
#pragma unroll
            for (int j = 0; j < 4; ++j) {
                int gr = row0 + 16 * m + lk * 4 + j;
                if (gr < M) {
                    float a = acc[m][j] + bv;
                    if (RES) a += RES[(long long)gr * DD + gc];
                    if (relu) a = fmaxf(a, 0.f);
                    if (Yb) Yb[(long long)gr * DD + gc] = f2bf(a);
                    else    Yf[(long long)gr * DD + gc] = a;
                }
            }
        }
    }
}

// ---------------- final projection: out[M,16] = X[M,128] @ Wo[128,16] + bo ----------------
__global__ __launch_bounds__(256) void k_gemm_out(
        const float* __restrict__ X, const float* __restrict__ Wo,
        const float* __restrict__ bo, float* __restrict__ Y, int M) {
    __shared__ float Wlds[128 * 16];
    int t = threadIdx.x;
    for (int i = t * 4; i < 128 * 16; i += 256 * 4) {
        *(float4*)&Wlds[i] = *(const float4*)&Wo[i];
    }
    __syncthreads();
    int r = blockIdx.x * blockDim.x + t;
    if (r < M) {
        float acc[16];
#pragma unroll
        for (int j = 0; j < 16; ++j) acc[j] = bo[j];
#pragma unroll
        for (int k = 0; k < 128; k += 4) {
            float4 x = *(const float4*)&X[(long long)r * DD + k];
#pragma unroll
            for (int j = 0; j < 16; ++j) {
                acc[j] += x.x * Wlds[(k + 0) * 16 + j] + x.y * Wlds[(k + 1) * 16 + j]
                        + x.z * Wlds[(k + 2) * 16 + j] + x.w * Wlds[(k + 3) * 16 + j];
            }
        }
#pragma unroll
        for (int j = 0; j < 16; j += 4) {
            float4 o = make_float4(acc[j], acc[j + 1], acc[j + 2], acc[j + 3]);
            *(float4*)&Y[(long long)r * CC + j] = o;
        }
    }
}

extern "C" void kernel_launch(void* const* d_in, const int* in_sizes, int n_in,
                              void* d_out, int out_size, void* d_ws, size_t ws_size,
                              hipStream_t stream) {
    const int*   src = (const int*)d_in[0];
    const int*   dst = (const int*)d_in[1];
    const float* inputs = (const float*)d_in[2];
    const float* ew  = (const float*)d_in[3];
    const float* W1  = (const float*)d_in[4];
    const float* b1  = (const float*)d_in[5];
    const float* W2  = (const float*)d_in[6];
    const float* b2  = (const float*)d_in[7];
    const float* W3  = (const float*)d_in[8];
    const float* b3  = (const float*)d_in[9];
    const float* W4  = (const float*)d_in[10];
    const float* b4  = (const float*)d_in[11];
    const float* Wr  = (const float*)d_in[12];
    const float* br  = (const float*)d_in[13];
    const float* Wo  = (const float*)d_in[14];
    const float* bo  = (const float*)d_in[15];
    float* out = (float*)d_out;

    // workspace layout
    char* p = (char*)d_ws;
    float* iso    = (float*)p; p += sizeof(float) * NN;
    float* isi    = (float*)p; p += sizeof(float) * NN;
    int*   cs     = (int*)p;   p += sizeof(int) * NN;      // reused as WHg
    int*   cd     = (int*)p;   p += sizeof(int) * NN;
    int*   cursor = (int*)p;   p += sizeof(int) * NN;
    int*   rowptr = (int*)p;   p += sizeof(int) * (NN + 1);
    int*   partial= (int*)p;   p += sizeof(int) * NBLK_SCAN;
    int*   pp     = (int*)p;   p += sizeof(int) * NBLK_SCAN;
    p = (char*)(((uintptr_t)p + 255) & ~(uintptr_t)255);
    int2*  pairs  = (int2*)p;  p += sizeof(int2) * EE;
    float* RES    = (float*)p; p += sizeof(float) * (size_t)NN * DD;
    float* G      = (float*)p; p += sizeof(float) * (size_t)NN * DD;
    float* X0     = (float*)p; p += sizeof(float) * (size_t)NN * DD;

    // aliases:
    unsigned short* WHg = (unsigned short*)cs;            // 160KB (cs + part of cd)
    unsigned short* WLg = WHg + 5 * 16384;                // 160KB
    unsigned int*   hist = (unsigned int*)G;              // 64 copies x 50K = 12.8MB, pre-layers
    unsigned short* H   = (unsigned short*)X0;            // bf16 intermediate (lower half of X0)
    unsigned short* Hin = H + (size_t)NN * DD;            // bf16 inputs (upper half of X0)

    const int GEMM_GRID = (NN + GTILE - 1) / GTILE;       // 782
    const int NRANGES = (NN + NRANGE - 1) / NRANGE;       // 4

    // ---- degrees via LDS-privatized histogram (no global atomics, no memset) ----
    hipMemsetAsync(cursor, 0, sizeof(int) * NN, stream);
    k_hist_lds<<<NRANGES * HCOPIES, 256, 0, stream>>>(src, dst, hist);
    k_reduce_deg<<<(NN + 255) / 256, 256, 0, stream>>>(hist, cd, iso, isi);
    k_blocksum<<<NBLK_SCAN, SBLK, 0, stream>>>(cd, partial);
    k_scanpartial<<<1, SBLK, 0, stream>>>(partial, pp, rowptr);
    k_writerowptr<<<NBLK_SCAN, SBLK, 0, stream>>>(cd, pp, rowptr);
    k_fill<<<(EE + 255) / 256, 256, 0, stream>>>(src, dst, ew, iso, isi, rowptr, cursor, pairs);

    // ---- prep bf16 weights + bf16 inputs ----
    k_prepw<<<5 * 128, 128, 0, stream>>>(W1, W2, W3, W4, Wr, WHg, WLg);
    k_tobf<<<(NN * DD / 4 + 255) / 256, 256, 0, stream>>>(inputs, Hin);

    // ---- res = inputs @ Wr + br (fp32 out) ----
    k_gemm_mfma<<<GEMM_GRID, 512, 0, stream>>>(inputs, WHg + 4 * 16384, WLg + 4 * 16384,
                                               br, nullptr, RES, nullptr, NN, 0);

    const float* bs[4] = {b1, b2, b3, b4};
    for (int l = 0; l < 4; ++l) {
        const unsigned short* Hs = (l == 0) ? Hin : H;
        k_gather_bf<<<(NN + 3) / 4, 256, 0, stream>>>(Hs, rowptr, pairs, G);

        if (l < 3) {
            k_gemm_mfma<<<GEMM_GRID, 512, 0, stream>>>(G, WHg + l * 16384, WLg + l * 16384,
                                                       bs[l], nullptr, nullptr, H, NN, 1);
        } else {
            k_gemm_mfma<<<GEMM_GRID, 512, 0, stream>>>(G, WHg + l * 16384, WLg + l * 16384,
                                                       bs[l], RES, X0, nullptr, NN, 1);
        }
    }

    k_gemm_out<<<(NN + 255) / 256, 256, 0, stream>>>(X0, Wo, bo, out, NN);
}

// Round 14
// 340.113 us; speedup vs baseline: 1.5213x; 1.0600x over previous
//
#include <hip/hip_runtime.h>
#include <hip/hip_fp16.h>

#define NN 50000
#define EE 800000
#define DD 128
#define CC 16
#define HCOPIES 64
#define NRANGE 16384   // nodes per LDS-hist range (64KB LDS)

typedef __attribute__((ext_vector_type(8))) short bf16x8;
typedef __attribute__((ext_vector_type(4))) float f32x4;

__device__ inline unsigned short f2bf(float x) {
    unsigned int u = __float_as_uint(x);
    unsigned int r = (u + 0x7FFFu + ((u >> 16) & 1u)) >> 16;
    return (unsigned short)r;
}
__device__ inline float bf2f(unsigned short h) {
    return __uint_as_float(((unsigned int)h) << 16);
}

// ---------------- LDS-privatized degree histogram (packed: src lo16, dst hi16) ----------------
__global__ __launch_bounds__(256) void k_hist_lds(
        const int* __restrict__ src, const int* __restrict__ dst,
        unsigned int* __restrict__ hist) {
    __shared__ unsigned int lds[NRANGE];
    const int t = threadIdx.x;
    const int r = blockIdx.x / HCOPIES;
    const int sub = blockIdx.x % HCOPIES;
    const int base = r * NRANGE;
    const int hi = min(base + NRANGE, NN) - base;   // range size (<= NRANGE)

    for (int i = t; i < NRANGE; i += 256) lds[i] = 0;
    __syncthreads();

    const int chunk = EE / HCOPIES;                 // 12500
    const int e0 = sub * chunk;
    const int e1 = e0 + chunk;
    for (int e = e0 + t; e < e1; e += 256) {
        int s = src[e];
        int d = dst[e];
        unsigned us = (unsigned)(s - base);
        unsigned ud = (unsigned)(d - base);
        if (us < (unsigned)hi) atomicAdd(&lds[us], 1u);
        if (ud < (unsigned)hi) atomicAdd(&lds[ud], 0x10000u);
    }
    __syncthreads();

    for (int i = t; i < hi; i += 256) hist[(size_t)sub * NN + base + i] = lds[i];
}

__global__ void k_reduce_deg(const unsigned int* __restrict__ hist,
                             int* __restrict__ cd,
                             float* __restrict__ iso, float* __restrict__ isi) {
    int i = blockIdx.x * blockDim.x + threadIdx.x;
    if (i < NN) {
        unsigned int sum = 0;
#pragma unroll
        for (int c = 0; c < HCOPIES; ++c) sum += hist[(size_t)c * NN + i];
        unsigned int csv = sum & 0xFFFFu;
        unsigned int cdv = sum >> 16;
        cd[i] = (int)cdv;
        iso[i] = rsqrtf(fmaxf((float)csv, 1.0f));
        isi[i] = rsqrtf(fmaxf((float)cdv, 1.0f));
    }
}

// ---------------- hierarchical exclusive scan: cd -> rowptr ----------------
#define SBLK 256
#define NBLK_SCAN ((NN + SBLK - 1) / SBLK)   // 196

__global__ __launch_bounds__(SBLK) void k_blocksum(const int* __restrict__ cnt,
                                                   int* __restrict__ partial) {
    __shared__ int s[SBLK];
    int t = threadIdx.x;
    int i = blockIdx.x * SBLK + t;
    int v = (i < NN) ? cnt[i] : 0;
    s[t] = v;
    __syncthreads();
    for (int off = SBLK / 2; off > 0; off >>= 1) {
        if (t < off) s[t] += s[t + off];
        __syncthreads();
    }
    if (t == 0) partial[blockIdx.x] = s[0];
}

__global__ __launch_bounds__(SBLK) void k_scanpartial(const int* __restrict__ partial,
                                                      int* __restrict__ pp,
                                                      int* __restrict__ rowptr) {
    __shared__ int s[SBLK];
    int t = threadIdx.x;
    int v = (t < NBLK_SCAN) ? partial[t] : 0;
    s[t] = v;
    __syncthreads();
    for (int off = 1; off < SBLK; off <<= 1) {
        int x = (t >= off) ? s[t - off] : 0;
        __syncthreads();
        s[t] += x;
        __syncthreads();
    }
    if (t < NBLK_SCAN) pp[t] = s[t] - v;   // exclusive prefix of block partials
    if (t == SBLK - 1) rowptr[NN] = s[t];  // grand total (== EE)
}

__global__ __launch_bounds__(SBLK) void k_writerowptr(const int* __restrict__ cnt,
                                                      const int* __restrict__ pp,
                                                      int* __restrict__ rowptr) {
    __shared__ int s[SBLK];
    int t = threadIdx.x;
    int i = blockIdx.x * SBLK + t;
    int v = (i < NN) ? cnt[i] : 0;
    s[t] = v;
    __syncthreads();
    for (int off = 1; off < SBLK; off <<= 1) {
        int x = (t >= off) ? s[t - off] : 0;
        __syncthreads();
        s[t] += x;
        __syncthreads();
    }
    if (i < NN) rowptr[i] = pp[blockIdx.x] + s[t] - v;
}

// ---------------- CSR fill, packed 4B: (src:16 | fp16 weight:16) ----------------
__global__ void k_fill(const int* __restrict__ src, const int* __restrict__ dst,
                       const float* __restrict__ ew, const float* __restrict__ iso,
                       const float* __restrict__ isi, const int* __restrict__ rowptr,
                       int* __restrict__ cursor, unsigned int* __restrict__ pairs) {
    int e = blockIdx.x * blockDim.x + threadIdx.x;
    if (e < EE) {
        int d = dst[e];
        int s = src[e];
        int pos = atomicAdd(&cursor[d], 1);
        float w = ew[e] * iso[s] * isi[d];
        unsigned short hw = __half_as_ushort(__float2half(w));
        unsigned int pk = ((unsigned)s & 0xFFFFu) | ((unsigned)hw << 16);
        int idx = rowptr[d] + pos;
        if ((unsigned)idx < EE) pairs[idx] = pk;   // defensive: never store wild
    }
}

// ---------------- inputs fp32 -> bf16 (for layer-0 gather + res GEMM) ----------------
__global__ __launch_bounds__(256) void k_tobf(const float* __restrict__ X,
                                              unsigned short* __restrict__ Hb) {
    int i = blockIdx.x * blockDim.x + threadIdx.x;   // NN*DD/4 threads
    if (i < NN * DD / 4) {
        float4 v = *(const float4*)&X[i * 4];
        ushort4 h;
        h.x = f2bf(v.x); h.y = f2bf(v.y); h.z = f2bf(v.z); h.w = f2bf(v.w);
        *(ushort4*)&Hb[i * 4] = h;
    }
}

// ---------------- CSR gather, bf16 src -> bf16 out, 8-deep pipelined ----------------
__global__ __launch_bounds__(256) void k_gather_bf(
        const unsigned short* __restrict__ H, const int* __restrict__ rowptr,
        const unsigned int* __restrict__ pairs, unsigned short* __restrict__ G) {
    int node = blockIdx.x * 4 + (threadIdx.x >> 6);
    if (node >= NN) return;
    int lane = threadIdx.x & 63;
    int c = lane * 2;
    int j = rowptr[node];
    int end = rowptr[node + 1];
    j = max(0, min(j, EE));
    end = max(j, min(end, EE));
    float2 a0 = make_float2(0.f, 0.f);
    float2 a1 = make_float2(0.f, 0.f);
    float2 a2 = make_float2(0.f, 0.f);
    float2 a3 = make_float2(0.f, 0.f);
    for (; j + 7 < end; j += 8) {
        unsigned p0 = pairs[j + 0];
        unsigned p1 = pairs[j + 1];
        unsigned p2 = pairs[j + 2];
        unsigned p3 = pairs[j + 3];
        unsigned p4 = pairs[j + 4];
        unsigned p5 = pairs[j + 5];
        unsigned p6 = pairs[j + 6];
        unsigned p7 = pairs[j + 7];
        int c0 = (p0 & 0xFFFFu) < NN ? (p0 & 0xFFFFu) : 0;
        int c1 = (p1 & 0xFFFFu) < NN ? (p1 & 0xFFFFu) : 0;
        int c2 = (p2 & 0xFFFFu) < NN ? (p2 & 0xFFFFu) : 0;
        int c3 = (p3 & 0xFFFFu) < NN ? (p3 & 0xFFFFu) : 0;
        int c4 = (p4 & 0xFFFFu) < NN ? (p4 & 0xFFFFu) : 0;
        int c5 = (p5 & 0xFFFFu) < NN ? (p5 & 0xFFFFu) : 0;
        int c6 = (p6 & 0xFFFFu) < NN ? (p6 & 0xFFFFu) : 0;
        int c7 = (p7 & 0xFFFFu) < NN ? (p7 & 0xFFFFu) : 0;
        ushort2 h0 = *(const ushort2*)&H[c0 * DD + c];
        ushort2 h1 = *(const ushort2*)&H[c1 * DD + c];
        ushort2 h2 = *(const ushort2*)&H[c2 * DD + c];
        ushort2 h3 = *(const ushort2*)&H[c3 * DD + c];
        ushort2 h4 = *(const ushort2*)&H[c4 * DD + c];
        ushort2 h5 = *(const ushort2*)&H[c5 * DD + c];
        ushort2 h6 = *(const ushort2*)&H[c6 * DD + c];
        ushort2 h7 = *(const ushort2*)&H[c7 * DD + c];
        float w0 = __half2float(__ushort_as_half((unsigned short)(p0 >> 16)));
        float w1 = __half2float(__ushort_as_half((unsigned short)(p1 >> 16)));
        float w2 = __half2float(__ushort_as_half((unsigned short)(p2 >> 16)));
        float w3 = __half2float(__ushort_as_half((unsigned short)(p3 >> 16)));
        float w4 = __half2float(__ushort_as_half((unsigned short)(p4 >> 16)));
        float w5 = __half2float(__ushort_as_half((unsigned short)(p5 >> 16)));
        float w6 = __half2float(__ushort_as_half((unsigned short)(p6 >> 16)));
        float w7 = __half2float(__ushort_as_half((unsigned short)(p7 >> 16)));
        a0.x = fmaf(bf2f(h0.x), w0, a0.x); a0.y = fmaf(bf2f(h0.y), w0, a0.y);
        a1.x = fmaf(bf2f(h1.x), w1, a1.x); a1.y = fmaf(bf2f(h1.y), w1, a1.y);
        a2.x = fmaf(bf2f(h2.x), w2, a2.x); a2.y = fmaf(bf2f(h2.y), w2, a2.y);
        a3.x = fmaf(bf2f(h3.x), w3, a3.x); a3.y = fmaf(bf2f(h3.y), w3, a3.y);
        a0.x = fmaf(bf2f(h4.x), w4, a0.x); a0.y = fmaf(bf2f(h4.y), w4, a0.y);
        a1.x = fmaf(bf2f(h5.x), w5, a1.x); a1.y = fmaf(bf2f(h5.y), w5, a1.y);
        a2.x = fmaf(bf2f(h6.x), w6, a2.x); a2.y = fmaf(bf2f(h6.y), w6, a2.y);
        a3.x = fmaf(bf2f(h7.x), w7, a3.x); a3.y = fmaf(bf2f(h7.y), w7, a3.y);
    }
    for (; j < end; ++j) {
        unsigned p0 = pairs[j];
        int c0 = (p0 & 0xFFFFu) < NN ? (p0 & 0xFFFFu) : 0;
        float w0 = __half2float(__ushort_as_half((unsigned short)(p0 >> 16)));
        ushort2 h0 = *(const ushort2*)&H[c0 * DD + c];
        a0.x = fmaf(bf2f(h0.x), w0, a0.x); a0.y = fmaf(bf2f(h0.y), w0, a0.y);
    }
    float ox = (a0.x + a1.x) + (a2.x + a3.x);
    float oy = (a0.y + a1.y) + (a2.y + a3.y);
    ushort2 o;
    o.x = f2bf(ox);
    o.y = f2bf(oy);
    *(ushort2*)&G[node * DD + c] = o;
}

// ---------------- W prep: fp32 [k][c] -> bf16 hi/lo, transposed layout [c][k] ----------------
__global__ __launch_bounds__(128) void k_prepw(
        const float* __restrict__ W1, const float* __restrict__ W2,
        const float* __restrict__ W3, const float* __restrict__ W4,
        const float* __restrict__ Wr,
        unsigned short* __restrict__ WH, unsigned short* __restrict__ WL) {
    int m = blockIdx.x >> 7;
    int c = blockIdx.x & 127;
    int k = threadIdx.x;
    const float* Wm = (m == 0) ? W1 : (m == 1) ? W2 : (m == 2) ? W3 : (m == 3) ? W4 : Wr;
    float x = Wm[k * 128 + c];
    unsigned short hi = f2bf(x);
    unsigned short lo = f2bf(x - bf2f(hi));
    int off = m * 16384 + c * 128 + k;
    WH[off] = hi;
    WL[off] = lo;
}

// ---------------- MFMA GEMM, bf16 input: W in registers, X-only LDS (16KB) ----------------
// 512 threads / 8 waves; block = 64 rows x 128 cols; wave w owns cols [16w,16w+16).
// acc += A*Bh + A*Bl   (W split-precision; A already bf16)
#define GTILE 64
__global__ __launch_bounds__(512) void k_gemm_mfma(
        const unsigned short* __restrict__ Xb,
        const unsigned short* __restrict__ Wh, const unsigned short* __restrict__ Wl,
        const float* __restrict__ bias, const float* __restrict__ RES,
        float* __restrict__ Yf, unsigned short* __restrict__ Yb, int M, int relu) {
    __shared__ unsigned short Xs[GTILE * 128];

    const int t = threadIdx.x;
    const int row0 = blockIdx.x * GTILE;

    const int lane = t & 63;
    const int wav = t >> 6;
    const int lr = lane & 15;
    const int lk = lane >> 4;

    bf16x8 bh[4], bl[4];
    {
        const int c = 16 * wav + lr;
#pragma unroll
        for (int k0 = 0; k0 < 4; ++k0) {
            int off = c * 128 + k0 * 32 + lk * 8;
            bh[k0] = *(const bf16x8*)&Wh[off];
            bl[k0] = *(const bf16x8*)&Wl[off];
        }
    }

    // stage 64 bf16 rows (ushort8 = 16B per thread-iter, coalesced), XOR-swizzled
    for (int i = t; i < GTILE * 16; i += 512) {
        int r = i >> 4;
        int c8 = i & 15;
        int gr = row0 + r;
        bf16x8 v = {0, 0, 0, 0, 0, 0, 0, 0};
        if (gr < M) v = *(const bf16x8*)&Xb[(size_t)gr * 128 + c8 * 8];
        int slot = (c8 * 8) ^ ((r & 7) << 3);
        *(bf16x8*)&Xs[r * 128 + slot] = v;
    }
    __syncthreads();

    f32x4 acc[4];
#pragma unroll
    for (int m = 0; m < 4; ++m) acc[m] = (f32x4){0.f, 0.f, 0.f, 0.f};

#pragma unroll
    for (int k0 = 0; k0 < 4; ++k0) {
        const int kbase = k0 * 32 + lk * 8;
        bf16x8 ah[4];
#pragma unroll
        for (int m = 0; m < 4; ++m) {
            int row = 16 * m + lr;
            ah[m] = *(const bf16x8*)&Xs[row * 128 + (kbase ^ ((row & 7) << 3))];
        }
#pragma unroll
        for (int m = 0; m < 4; ++m) {
            acc[m] = __builtin_amdgcn_mfma_f32_16x16x32_bf16(ah[m], bh[k0], acc[m], 0, 0, 0);
            acc[m] = __builtin_amdgcn_mfma_f32_16x16x32_bf16(ah[m], bl[k0], acc[m], 0, 0, 0);
        }
    }

    {
        int gc = 16 * wav + lr;
        float bv = bias[gc];
#pragma unroll
        for (int m = 0; m < 4; ++m) {
#pragma unroll
            for (int j = 0; j < 4; ++j) {
                int gr = row0 + 16 * m + lk * 4 + j;
                if (gr < M) {
                    float a = acc[m][j] + bv;
                    if (RES) a += RES[(long long)gr * DD + gc];
                    if (relu) a = fmaxf(a, 0.f);
                    if (Yb) Yb[(long long)gr * DD + gc] = f2bf(a);
                    else    Yf[(long long)gr * DD + gc] = a;
                }
            }
        }
    }
}

// ---------------- final projection: out[M,16] = X[M,128] @ Wo[128,16] + bo ----------------
__global__ __launch_bounds__(256) void k_gemm_out(
        const float* __restrict__ X, const float* __restrict__ Wo,
        const float* __restrict__ bo, float* __restrict__ Y, int M) {
    __shared__ float Wlds[128 * 16];
    int t = threadIdx.x;
    for (int i = t * 4; i < 128 * 16; i += 256 * 4) {
        *(float4*)&Wlds[i] = *(const float4*)&Wo[i];
    }
    __syncthreads();
    int r = blockIdx.x * blockDim.x + t;
    if (r < M) {
        float acc[16];
#pragma unroll
        for (int j = 0; j < 16; ++j) acc[j] = bo[j];
#pragma unroll
        for (int k = 0; k < 128; k += 4) {
            float4 x = *(const float4*)&X[(long long)r * DD + k];
#pragma unroll
            for (int j = 0; j < 16; ++j) {
                acc[j] += x.x * Wlds[(k + 0) * 16 + j] + x.y * Wlds[(k + 1) * 16 + j]
                        + x.z * Wlds[(k + 2) * 16 + j] + x.w * Wlds[(k + 3) * 16 + j];
            }
        }
#pragma unroll
        for (int j = 0; j < 16; j += 4) {
            float4 o = make_float4(acc[j], acc[j + 1], acc[j + 2], acc[j + 3]);
            *(float4*)&Y[(long long)r * CC + j] = o;
        }
    }
}

extern "C" void kernel_launch(void* const* d_in, const int* in_sizes, int n_in,
                              void* d_out, int out_size, void* d_ws, size_t ws_size,
                              hipStream_t stream) {
    const int*   src = (const int*)d_in[0];
    const int*   dst = (const int*)d_in[1];
    const float* inputs = (const float*)d_in[2];
    const float* ew  = (const float*)d_in[3];
    const float* W1  = (const float*)d_in[4];
    const float* b1  = (const float*)d_in[5];
    const float* W2  = (const float*)d_in[6];
    const float* b2  = (const float*)d_in[7];
    const float* W3  = (const float*)d_in[8];
    const float* b3  = (const float*)d_in[9];
    const float* W4  = (const float*)d_in[10];
    const float* b4  = (const float*)d_in[11];
    const float* Wr  = (const float*)d_in[12];
    const float* br  = (const float*)d_in[13];
    const float* Wo  = (const float*)d_in[14];
    const float* bo  = (const float*)d_in[15];
    float* out = (float*)d_out;

    // workspace layout
    char* p = (char*)d_ws;
    float* iso    = (float*)p; p += sizeof(float) * NN;
    float* isi    = (float*)p; p += sizeof(float) * NN;
    int*   cs     = (int*)p;   p += sizeof(int) * NN;      // reused as WHg
    int*   cd     = (int*)p;   p += sizeof(int) * NN;
    int*   cursor = (int*)p;   p += sizeof(int) * NN;
    int*   rowptr = (int*)p;   p += sizeof(int) * (NN + 1);
    int*   partial= (int*)p;   p += sizeof(int) * NBLK_SCAN;
    int*   pp     = (int*)p;   p += sizeof(int) * NBLK_SCAN;
    p = (char*)(((uintptr_t)p + 255) & ~(uintptr_t)255);
    unsigned int* pairs = (unsigned int*)p; p += sizeof(unsigned int) * EE;
    p = (char*)(((uintptr_t)p + 255) & ~(uintptr_t)255);
    float* RES    = (float*)p; p += sizeof(float) * (size_t)NN * DD;
    float* G      = (float*)p; p += sizeof(float) * (size_t)NN * DD;
    float* X0     = (float*)p; p += sizeof(float) * (size_t)NN * DD;

    // aliases:
    unsigned short* WHg = (unsigned short*)cs;            // 160KB (cs + part of cd)
    unsigned short* WLg = WHg + 5 * 16384;                // 160KB
    unsigned int*   hist = (unsigned int*)G;              // 64 copies x 50K = 12.8MB, pre-layers
    unsigned short* Gb  = (unsigned short*)G;             // bf16 gather output (12.8MB)
    unsigned short* H   = (unsigned short*)X0;            // bf16 intermediate (lower half of X0)
    unsigned short* Hin = H + (size_t)NN * DD;            // bf16 inputs (upper half of X0)

    const int GEMM_GRID = (NN + GTILE - 1) / GTILE;       // 782
    const int NRANGES = (NN + NRANGE - 1) / NRANGE;       // 4

    // ---- degrees via LDS-privatized histogram ----
    hipMemsetAsync(cursor, 0, sizeof(int) * NN, stream);
    k_hist_lds<<<NRANGES * HCOPIES, 256, 0, stream>>>(src, dst, hist);
    k_reduce_deg<<<(NN + 255) / 256, 256, 0, stream>>>(hist, cd, iso, isi);
    k_blocksum<<<NBLK_SCAN, SBLK, 0, stream>>>(cd, partial);
    k_scanpartial<<<1, SBLK, 0, stream>>>(partial, pp, rowptr);
    k_writerowptr<<<NBLK_SCAN, SBLK, 0, stream>>>(cd, pp, rowptr);
    k_fill<<<(EE + 255) / 256, 256, 0, stream>>>(src, dst, ew, iso, isi, rowptr, cursor, pairs);

    // ---- prep bf16 weights + bf16 inputs ----
    k_prepw<<<5 * 128, 128, 0, stream>>>(W1, W2, W3, W4, Wr, WHg, WLg);
    k_tobf<<<(NN * DD / 4 + 255) / 256, 256, 0, stream>>>(inputs, Hin);

    // ---- res = bf16(inputs) @ Wr + br (fp32 out) ----
    k_gemm_mfma<<<GEMM_GRID, 512, 0, stream>>>(Hin, WHg + 4 * 16384, WLg + 4 * 16384,
                                               br, nullptr, RES, nullptr, NN, 0);

    const float* bs[4] = {b1, b2, b3, b4};
    for (int l = 0; l < 4; ++l) {
        const unsigned short* Hs = (l == 0) ? Hin : H;
        k_gather_bf<<<(NN + 3) / 4, 256, 0, stream>>>(Hs, rowptr, pairs, Gb);

        if (l < 3) {
            k_gemm_mfma<<<GEMM_GRID, 512, 0, stream>>>(Gb, WHg + l * 16384, WLg + l * 16384,
                                                       bs[l], nullptr, nullptr, H, NN, 1);
        } else {
            k_gemm_mfma<<<GEMM_GRID, 512, 0, stream>>>(Gb, WHg + l * 16384, WLg + l * 16384,
                                                       bs[l], RES, X0, nullptr, NN, 1);
        }
    }

    k_gemm_out<<<(NN + 255) / 256, 256, 0, stream>>>(X0, Wo, bo, out, NN);
}